// Round 2
// baseline (1665.813 us; speedup 1.0000x reference)
//
#include <hip/hip_runtime.h>

typedef unsigned short ushort;
typedef unsigned int uint;
typedef __attribute__((ext_vector_type(8))) short short8;
typedef __attribute__((ext_vector_type(4))) float float4v;

#define DEV __device__ __forceinline__

DEV float b2f(ushort u) {
    union { uint i; float f; } v; v.i = ((uint)u) << 16; return v.f;
}
DEV ushort f2b(float f) {
    union { float f; uint i; } v; v.f = f;
    uint x = v.i;
    uint r = x + 0x7fffu + ((x >> 16) & 1u);
    return (ushort)(r >> 16);
}
DEV float leaky(float x, float s) { return x >= 0.f ? x : s * x; }

// ---------------- dtype sniff: 1 = fp32 inputs, 0 = bf16 inputs ----------------
__global__ void sniff_kernel(const ushort* __restrict__ x, int* __restrict__ flag) {
    int lane = threadIdx.x & 63;
    int cnt = 0;
    for (int j = 0; j < 8; j++) {
        ushort u = x[(lane * 8 + j) * 2];  // even ushort indices 0..1022
        int e = (u >> 7) & 0xFF;
        if (e >= 100 && e <= 140) cnt++;   // "reasonable bf16 value" exponent band
    }
#pragma unroll
    for (int m = 1; m < 64; m <<= 1) cnt += __shfl_xor(cnt, m, 64);
    if (threadIdx.x == 0) *flag = (cnt < 256) ? 1 : 0;
}

struct ConvArgs {
    const void* s[36];
    float* d[36];
    int n[36];
};

__global__ __launch_bounds__(256) void convert_kernel(ConvArgs a, const int* __restrict__ flag) {
    int ai = blockIdx.y;
    int n = a.n[ai];
    const void* s = a.s[ai];
    float* d = a.d[ai];
    bool fp32 = (*flag != 0);
    int stride = gridDim.x * blockDim.x;
    for (int i = blockIdx.x * blockDim.x + threadIdx.x; i < n; i += stride)
        d[i] = fp32 ? ((const float*)s)[i] : b2f(((const ushort*)s)[i]);
}

// ---------------- CSR build ----------------
__global__ __launch_bounds__(256) void hist_kernel(const int* __restrict__ dst,
                                                   int* __restrict__ cnt, int E) {
    int stride = gridDim.x * blockDim.x;
    for (int i = blockIdx.x * blockDim.x + threadIdx.x; i < E; i += stride)
        atomicAdd(&cnt[dst[i]], 1);
}

__global__ __launch_bounds__(1024) void scan_kernel(const int* __restrict__ cnt,
                                                    int* __restrict__ off, int n) {
    __shared__ int ssum[1024];
    int t = threadIdx.x;
    int L = (n + 1023) >> 10;
    int lo = t * L, hi = min(lo + L, n);
    int s = 0;
    for (int i = lo; i < hi; i++) s += cnt[i];
    ssum[t] = s;
    __syncthreads();
    for (int d = 1; d < 1024; d <<= 1) {
        int add = 0;
        if (t >= d) add = ssum[t - d];
        __syncthreads();
        if (t >= d) ssum[t] += add;
        __syncthreads();
    }
    int run = ssum[t] - s;
    for (int i = lo; i < hi; i++) { off[i] = run; run += cnt[i]; }
    if (t == 1023) off[n] = run;
}

__global__ __launch_bounds__(256) void scatter_kernel(const int* __restrict__ src,
                                                      const int* __restrict__ dst,
                                                      const int* __restrict__ off,
                                                      int* __restrict__ cursor,
                                                      int* __restrict__ csr, int E) {
    int stride = gridDim.x * blockDim.x;
    for (int i = blockIdx.x * blockDim.x + threadIdx.x; i < E; i += stride) {
        int d = dst[i];
        int pos = off[d] + atomicAdd(&cursor[d], 1);
        csr[pos] = src[i];
    }
}

// ---------------- layer-1 projection (K=5) + el/er ----------------
__global__ __launch_bounds__(256) void proj1_kernel(const float* __restrict__ x,
                                                    const float* __restrict__ W,
                                                    const float* __restrict__ al,
                                                    const float* __restrict__ ar,
                                                    float* __restrict__ h,
                                                    float* __restrict__ el,
                                                    float* __restrict__ er, int Nn) {
    int t = threadIdx.x;
    int head = t >> 6, lane = t & 63;
    float wv[5];
#pragma unroll
    for (int k = 0; k < 5; k++) wv[k] = W[k * 256 + t];
    float alv = al[t];  // al[head*64+lane] == al[t]
    float arv = ar[t];
    int n0 = blockIdx.x * 4;
    int n1 = min(n0 + 4, Nn);
    for (int n = n0; n < n1; n++) {
        float acc = 0.f;
#pragma unroll
        for (int k = 0; k < 5; k++) acc += x[n * 5 + k] * wv[k];
        h[(size_t)n * 256 + t] = acc;
        float pl = acc * alv, pr = acc * arv;
#pragma unroll
        for (int m = 1; m < 64; m <<= 1) {
            pl += __shfl_xor(pl, m, 64);
            pr += __shfl_xor(pr, m, 64);
        }
        if (lane == 0) { el[n * 4 + head] = pl; er[n * 4 + head] = pr; }
    }
}

// ---------------- el/er from projected features ----------------
template <int H, int LOGD, int HD>
__global__ __launch_bounds__(256) void elr_kernel(const float* __restrict__ h,
                                                  const float* __restrict__ al,
                                                  const float* __restrict__ ar,
                                                  float* __restrict__ el,
                                                  float* __restrict__ er, int Nn) {
    int gw = blockIdx.x * 4 + (threadIdx.x >> 6);
    if (gw >= Nn) return;
    int lane = threadIdx.x & 63;
    constexpr int D = 1 << LOGD;
    constexpr int ND = (HD + 63) / 64;
#pragma unroll
    for (int j = 0; j < ND; j++) {
        int d = lane + 64 * j;
        bool valid = d < HD;
        float hv = 0.f, av = 0.f, rv = 0.f;
        if (valid) { hv = h[(size_t)gw * HD + d]; av = al[d]; rv = ar[d]; }
        float pl = hv * av, pr = hv * rv;
#pragma unroll
        for (int m = 1; m < D && m < 64; m <<= 1) {
            pl += __shfl_xor(pl, m, 64);
            pr += __shfl_xor(pr, m, 64);
        }
        int hd = d >> LOGD;
        if (valid && (d & (D - 1)) == 0) { el[gw * H + hd] = pl; er[gw * H + hd] = pr; }
    }
}

// ---------------- GAT edge aggregation (CSR, one wave per dst) ----------------
template <int H, int LOGD, int HD>
__global__ __launch_bounds__(256) void aggr_kernel(const float* __restrict__ h,
                                                   const float* __restrict__ el,
                                                   const float* __restrict__ er,
                                                   const int* __restrict__ off,
                                                   const int* __restrict__ csr,
                                                   float* __restrict__ out, int Nn,
                                                   float oslope) {
    int gw = blockIdx.x * 4 + (threadIdx.x >> 6);
    if (gw >= Nn) return;
    int lane = threadIdx.x & 63;
    constexpr int ND = (HD + 63) / 64;
    float acc[ND];
    float s[H], erd[H];
#pragma unroll
    for (int j = 0; j < ND; j++) acc[j] = 0.f;
#pragma unroll
    for (int hh = 0; hh < H; hh++) { s[hh] = 0.f; erd[hh] = er[gw * H + hh]; }
    int e1 = off[gw + 1];
    for (int e = off[gw]; e < e1; e++) {
        int src = csr[e];
        float w_[H];
#pragma unroll
        for (int hh = 0; hh < H; hh++) {
            float ev = el[src * H + hh] + erd[hh];
            ev = ev >= 0.f ? ev : 0.2f * ev;
            ev = fminf(ev, 80.f);
            float wv = __expf(ev);
            w_[hh] = wv;
            s[hh] += wv;
        }
#pragma unroll
        for (int j = 0; j < ND; j++) {
            int d = lane + 64 * j;
            if (d < HD) acc[j] += w_[d >> LOGD] * h[(size_t)src * HD + d];
        }
    }
#pragma unroll
    for (int j = 0; j < ND; j++) {
        int d = lane + 64 * j;
        if (d < HD) {
            float v = acc[j] / fmaxf(s[d >> LOGD], 1e-9f);
            out[(size_t)gw * HD + d] = leaky(v, oslope);
        }
    }
}

// final GAT layer: H=2, D=32, HD=64, head-mean + atomic segment-sum
__global__ __launch_bounds__(256) void aggr_mean_kernel(const float* __restrict__ h,
                                                        const float* __restrict__ el,
                                                        const float* __restrict__ er,
                                                        const int* __restrict__ off,
                                                        const int* __restrict__ csr,
                                                        const int* __restrict__ gid,
                                                        float* __restrict__ out_sum,
                                                        float* __restrict__ out_cnt,
                                                        int Nn) {
    int gw = blockIdx.x * 4 + (threadIdx.x >> 6);
    if (gw >= Nn) return;
    int lane = threadIdx.x & 63;
    float erd0 = er[gw * 2], erd1 = er[gw * 2 + 1];
    float acc = 0.f, s0 = 0.f, s1 = 0.f;
    int e1 = off[gw + 1];
    for (int e = off[gw]; e < e1; e++) {
        int src = csr[e];
        float e0 = el[src * 2] + erd0;      e0 = e0 >= 0.f ? e0 : 0.2f * e0;
        float e1v = el[src * 2 + 1] + erd1; e1v = e1v >= 0.f ? e1v : 0.2f * e1v;
        float w0 = __expf(fminf(e0, 80.f)), w1 = __expf(fminf(e1v, 80.f));
        s0 += w0; s1 += w1;
        acc += (lane < 32 ? w0 : w1) * h[(size_t)src * 64 + lane];
    }
    float ss = lane < 32 ? s0 : s1;
    float y = acc / fmaxf(ss, 1e-9f);
    float part = __shfl_xor(y, 32, 64);
    float hm = 0.5f * (y + part);
    if (lane < 32) {
        int base = gid ? gid[gw] * 32 : 0;
        atomicAdd(&out_sum[base + lane], hm);
    }
    if (lane == 0 && out_cnt) atomicAdd(&out_cnt[gid[gw]], 1.0f);
}

// ---------------- GraphNorm: column stats + apply ----------------
__global__ void colstats_kernel(const float* __restrict__ x,
                                float* __restrict__ sum,
                                float* __restrict__ sumsq, int Nn) {
    int C = blockDim.x, c = threadIdx.x;
    float ls = 0.f, lq = 0.f;
    for (int r = blockIdx.x; r < Nn; r += gridDim.x) {
        float v = x[(size_t)r * C + c];
        ls += v; lq += v * v;
    }
    atomicAdd(&sum[c], ls);
    atomicAdd(&sumsq[c], lq);
}

__global__ void gnorm_apply_kernel(float* __restrict__ x,
                                   const float* __restrict__ sum,
                                   const float* __restrict__ sumsq,
                                   const float* __restrict__ g,
                                   const float* __restrict__ b,
                                   const float* __restrict__ a, int Nn) {
    int C = blockDim.x, c = threadIdx.x;
    float invn = 1.f / (float)Nn;
    float mu = sum[c] * invn, ex2 = sumsq[c] * invn;
    float av = a[c];
    float var = ex2 - 2.f * av * mu * mu + av * av * mu * mu;
    float sc = g[c] * rsqrtf(var + 1e-5f);
    float sh = b[c] - sc * av * mu;
    for (int r = blockIdx.x; r < Nn; r += gridDim.x) {
        size_t i = (size_t)r * C + c;
        x[i] = x[i] * sc + sh;
    }
}

// GraphNorm apply for readout: writes d_out (per flag) + fp32 mesh input
__global__ void gnorm_apply_ro_kernel(const float* __restrict__ x,
                                      const float* __restrict__ sum,
                                      const float* __restrict__ sumsq,
                                      const float* __restrict__ g,
                                      const float* __restrict__ b,
                                      const float* __restrict__ a,
                                      void* __restrict__ doutv,
                                      const int* __restrict__ flag,
                                      float* __restrict__ rof, int Nn) {
    int c = threadIdx.x;  // C = 32
    float invn = 1.f / (float)Nn;
    float mu = sum[c] * invn, ex2 = sumsq[c] * invn;
    float av = a[c];
    float var = ex2 - 2.f * av * mu * mu + av * av * mu * mu;
    float sc = g[c] * rsqrtf(var + 1e-5f);
    float sh = b[c] - sc * av * mu;
    bool fp32 = (*flag != 0);
    for (int r = blockIdx.x; r < Nn; r += gridDim.x) {
        int i = r * 32 + c;
        float v = x[i] * sc + sh;
        rof[i] = v;
        if (fp32) ((float*)doutv)[15 + i] = v;
        else      ((ushort*)doutv)[15 + i] = f2b(v);
    }
}

// ---------------- readout: segment-mean @ pcls + leaky ----------------
__global__ __launch_bounds__(256) void readout_kernel(const float* __restrict__ ro_sum,
                                                      const float* __restrict__ ro_cnt,
                                                      const float* __restrict__ pcls,
                                                      float* __restrict__ ro_lin, int NGc) {
    int idx = blockIdx.x * blockDim.x + threadIdx.x;
    int g = idx >> 5, c = idx & 31;
    if (g >= NGc) return;
    float inv = 1.f / fmaxf(ro_cnt[g], 1.f);
    float acc = 0.f;
#pragma unroll
    for (int k = 0; k < 32; k++) acc += ro_sum[g * 32 + k] * inv * pcls[k * 32 + c];
    ro_lin[g * 32 + c] = leaky(acc, 0.01f);
}

// ---------------- MFMA GEMM: C[M,N] = A[M,K] @ B[K,N], fp32 in/out (bf16 MFMA) ----------------
template <int K, int N>
__global__ __launch_bounds__(256) void gemm_kernel(const float* __restrict__ A,
                                                   const float* __restrict__ B,
                                                   float* __restrict__ C, int M) {
    constexpr int NT = N / 16;
    constexpr int AROW = 40;  // multiple of 8 -> frag reads stay 16B-aligned
    __shared__ __align__(16) ushort Alds[64 * AROW];
    __shared__ __align__(16) ushort Blds[32 * N];  // swizzled [k/8][n][k%8]
    int tid = threadIdx.x;
    int w = tid >> 6, lane = tid & 63, q = lane >> 4, l16 = lane & 15;
    int m0 = blockIdx.x * 64;
    float4v acc[NT];
#pragma unroll
    for (int nt = 0; nt < NT; nt++) acc[nt] = (float4v){0.f, 0.f, 0.f, 0.f};

    for (int kc = 0; kc < K; kc += 32) {
        __syncthreads();
        {  // stage A: 64 rows x 32 k (fp32 -> bf16)
#pragma unroll
            for (int it = 0; it < 2; it++) {
                int idx = it * 256 + tid;       // 0..511
                int r = idx >> 3;
                int c4 = (idx & 7) * 4;
                int gr = m0 + r;
                float4 av = {0.f, 0.f, 0.f, 0.f};
                if (gr < M) av = *(const float4*)(A + (size_t)gr * K + kc + c4);
                uint2 pk;
                pk.x = (uint)f2b(av.x) | ((uint)f2b(av.y) << 16);
                pk.y = (uint)f2b(av.z) | ((uint)f2b(av.w) << 16);
                *(uint2*)(&Alds[r * AROW + c4]) = pk;
            }
        }
        {  // stage B swizzled (fp32 -> bf16)
            constexpr int PAIRS = 16 * N;  // 32*N/2
#pragma unroll
            for (int p0 = 0; p0 < PAIRS; p0 += 256) {
                int p = p0 + tid;
                int k_ = p / (N / 2);
                int n0 = (p % (N / 2)) * 2;
                float2 bv = *(const float2*)(B + (size_t)(kc + k_) * N + n0);
                int base = (((k_ >> 3) * N + n0) << 3) + (k_ & 7);
                Blds[base] = f2b(bv.x);
                Blds[base + 8] = f2b(bv.y);
            }
        }
        __syncthreads();
        short8 a = *(const short8*)(&Alds[(w * 16 + l16) * AROW + q * 8]);
#pragma unroll
        for (int nt = 0; nt < NT; nt++) {
            short8 b = *(const short8*)(&Blds[(q * N + nt * 16 + l16) * 8]);
            acc[nt] = __builtin_amdgcn_mfma_f32_16x16x32_bf16(a, b, acc[nt], 0, 0, 0);
        }
    }
#pragma unroll
    for (int nt = 0; nt < NT; nt++) {
#pragma unroll
        for (int i = 0; i < 4; i++) {
            int row = m0 + w * 16 + q * 4 + i;
            if (row < M) C[(size_t)row * N + nt * 16 + l16] = acc[nt][i];
        }
    }
}

// ---------------- final: node-mean @ mcls ----------------
__global__ __launch_bounds__(64) void final_kernel(const float* __restrict__ msum,
                                                   const float* __restrict__ mcls,
                                                   void* __restrict__ doutv,
                                                   const int* __restrict__ flag, int Nm) {
    int t = threadIdx.x;
    if (t < 15) {
        float inv = 1.f / (float)Nm;
        float acc = 0.f;
#pragma unroll
        for (int c = 0; c < 32; c++) acc += msum[c] * inv * mcls[c * 15 + t];
        if (*flag) ((float*)doutv)[t] = acc;
        else       ((ushort*)doutv)[t] = f2b(acc);
    }
}

extern "C" void kernel_launch(void* const* d_in, const int* in_sizes, int n_in,
                              void* d_out, int out_size, void* d_ws, size_t ws_size,
                              hipStream_t stream) {
    const int NP = 100000, NG = 2000, EP = 800000, NM = 2000, EM = 32000;

    const int* patch_src = (const int*)d_in[1];
    const int* patch_dst = (const int*)d_in[2];
    const int* patch_gid = (const int*)d_in[3];
    const int* mesh_src = (const int*)d_in[4];
    const int* mesh_dst = (const int*)d_in[5];

    // ---- workspace carve (256B aligned) ----
    char* p = (char*)d_ws;
    auto alloc = [&](size_t bytes) -> char* {
        char* r = p;
        p += (bytes + 255) & ~(size_t)255;
        return r;
    };
    char* zbase = p;  // zero-initialized region (one memset)
    int* cnt_p = (int*)alloc((size_t)NP * 4);
    int* cursor_p = (int*)alloc((size_t)NP * 4);
    int* cnt_m = (int*)alloc((size_t)NM * 4);
    int* cursor_m = (int*)alloc((size_t)NM * 4);
    float* ro_sum = (float*)alloc((size_t)NG * 32 * 4);
    float* ro_cnt = (float*)alloc((size_t)NG * 4);
    float* msum = (float*)alloc(32 * 4);
    float* colbuf = (float*)alloc(6 * 512 * 4);
    size_t zbytes = (size_t)(p - zbase);
    int* flag = (int*)alloc(256);
    int* off_p = (int*)alloc((size_t)(NP + 1) * 4);
    int* off_m = (int*)alloc((size_t)(NM + 1) * 4);
    int* csr_p = (int*)alloc((size_t)EP * 4);
    int* csr_m = (int*)alloc((size_t)EM * 4);
    float* el = (float*)alloc((size_t)NP * 4 * 4);
    float* er = (float*)alloc((size_t)NP * 4 * 4);
    float* hbuf = (float*)alloc((size_t)NP * 256 * 4);
    float* gbuf = (float*)alloc((size_t)NP * 256 * 4);
    float* hm = (float*)alloc((size_t)NM * 256 * 4);
    float* gm = (float*)alloc((size_t)NM * 256 * 4);
    float* elm = (float*)alloc((size_t)NM * 4 * 4);
    float* erm = (float*)alloc((size_t)NM * 4 * 4);
    float* ro_lin = (float*)alloc((size_t)NG * 32 * 4);
    float* ro_f = (float*)alloc((size_t)NG * 32 * 4);

    // converted fp32 copies of all float inputs
    ConvArgs ca;
    float* convp[36];
    int conv_idx[36];
    conv_idx[0] = 0;
    for (int i = 1; i < 36; i++) conv_idx[i] = 5 + i;  // inputs 6..40
    for (int j = 0; j < 36; j++) {
        int ii = conv_idx[j];
        int n = in_sizes[ii];
        float* dd = (float*)alloc((size_t)n * 4);
        ca.s[j] = d_in[ii];
        ca.d[j] = dd;
        ca.n[j] = n;
        convp[j] = dd;
    }
    const float* xf = convp[0];
    const float *pW1f = convp[1], *pal1f = convp[2], *par1f = convp[3];
    const float *pg1_gf = convp[4], *pg1_bf = convp[5], *pg1_af = convp[6];
    const float *pW2f = convp[7], *pal2f = convp[8], *par2f = convp[9];
    const float *pg2_gf = convp[10], *pg2_bf = convp[11], *pg2_af = convp[12];
    const float *pW3f = convp[13], *pal3f = convp[14], *par3f = convp[15];
    const float* pclsf = convp[16];
    const float *rn_gf = convp[17], *rn_bf2 = convp[18], *rn_af = convp[19];
    const float *mW1f = convp[20], *mal1f = convp[21], *mar1f = convp[22];
    const float *mg1_gf = convp[23], *mg1_bf = convp[24], *mg1_af = convp[25];
    const float *mW2f = convp[26], *mal2f = convp[27], *mar2f = convp[28];
    const float *mg2_gf = convp[29], *mg2_bf = convp[30], *mg2_af = convp[31];
    const float *mW3f = convp[32], *mal3f = convp[33], *mar3f = convp[34];
    const float* mclsf = convp[35];

    hipMemsetAsync(zbase, 0, zbytes, stream);
    sniff_kernel<<<1, 64, 0, stream>>>((const ushort*)d_in[0], flag);
    convert_kernel<<<dim3(16, 36), 256, 0, stream>>>(ca, flag);

    // ---- CSR build (patch + mesh) ----
    hist_kernel<<<512, 256, 0, stream>>>(patch_dst, cnt_p, EP);
    hist_kernel<<<64, 256, 0, stream>>>(mesh_dst, cnt_m, EM);
    scan_kernel<<<1, 1024, 0, stream>>>(cnt_p, off_p, NP);
    scan_kernel<<<1, 1024, 0, stream>>>(cnt_m, off_m, NM);
    scatter_kernel<<<512, 256, 0, stream>>>(patch_src, patch_dst, off_p, cursor_p, csr_p, EP);
    scatter_kernel<<<64, 256, 0, stream>>>(mesh_src, mesh_dst, off_m, cursor_m, csr_m, EM);

    int gP = (NP + 3) / 4, gM = (NM + 3) / 4;
    int gT = (NP + 63) / 64, gTm = (NM + 63) / 64;
    float* cb0 = colbuf + 0 * 512;
    float* cb1 = colbuf + 1 * 512;
    float* cb2 = colbuf + 2 * 512;
    float* cb3 = colbuf + 3 * 512;
    float* cb4 = colbuf + 4 * 512;

    // ---- patch GAT layer 1 (H=4, D=64) ----
    proj1_kernel<<<gP, 256, 0, stream>>>(xf, pW1f, pal1f, par1f, hbuf, el, er, NP);
    aggr_kernel<4, 6, 256><<<gP, 256, 0, stream>>>(hbuf, el, er, off_p, csr_p, gbuf, NP, 0.01f);
    colstats_kernel<<<256, 256, 0, stream>>>(gbuf, cb0, cb0 + 256, NP);
    gnorm_apply_kernel<<<256, 256, 0, stream>>>(gbuf, cb0, cb0 + 256, pg1_gf, pg1_bf, pg1_af, NP);

    // ---- patch GAT layer 2 (H=3, D=64) ----
    gemm_kernel<256, 192><<<gT, 256, 0, stream>>>(gbuf, pW2f, hbuf, NP);
    elr_kernel<3, 6, 192><<<gP, 256, 0, stream>>>(hbuf, pal2f, par2f, el, er, NP);
    aggr_kernel<3, 6, 192><<<gP, 256, 0, stream>>>(hbuf, el, er, off_p, csr_p, gbuf, NP, 0.01f);
    colstats_kernel<<<256, 192, 0, stream>>>(gbuf, cb1, cb1 + 256, NP);
    gnorm_apply_kernel<<<256, 192, 0, stream>>>(gbuf, cb1, cb1 + 256, pg2_gf, pg2_bf, pg2_af, NP);

    // ---- patch GAT layer 3 (H=2, D=32) + head-mean + segment readout ----
    gemm_kernel<192, 64><<<gT, 256, 0, stream>>>(gbuf, pW3f, hbuf, NP);
    elr_kernel<2, 5, 64><<<gP, 256, 0, stream>>>(hbuf, pal3f, par3f, el, er, NP);
    aggr_mean_kernel<<<gP, 256, 0, stream>>>(hbuf, el, er, off_p, csr_p, patch_gid,
                                             ro_sum, ro_cnt, NP);

    // ---- readout: mean -> @pcls -> leaky -> GraphNorm (output 1 + mesh input) ----
    readout_kernel<<<(NG * 32 + 255) / 256, 256, 0, stream>>>(ro_sum, ro_cnt, pclsf, ro_lin, NG);
    colstats_kernel<<<64, 32, 0, stream>>>(ro_lin, cb2, cb2 + 256, NG);
    gnorm_apply_ro_kernel<<<64, 32, 0, stream>>>(ro_lin, cb2, cb2 + 256, rn_gf, rn_bf2, rn_af,
                                                 d_out, flag, ro_f, NG);

    // ---- mesh GAT layer 1 (H=4, D=64) ----
    gemm_kernel<32, 256><<<gTm, 256, 0, stream>>>(ro_f, mW1f, hm, NM);
    elr_kernel<4, 6, 256><<<gM, 256, 0, stream>>>(hm, mal1f, mar1f, elm, erm, NM);
    aggr_kernel<4, 6, 256><<<gM, 256, 0, stream>>>(hm, elm, erm, off_m, csr_m, gm, NM, 0.01f);
    colstats_kernel<<<64, 256, 0, stream>>>(gm, cb3, cb3 + 256, NM);
    gnorm_apply_kernel<<<64, 256, 0, stream>>>(gm, cb3, cb3 + 256, mg1_gf, mg1_bf, mg1_af, NM);

    // ---- mesh GAT layer 2 (H=3, D=32) ----
    gemm_kernel<256, 96><<<gTm, 256, 0, stream>>>(gm, mW2f, hm, NM);
    elr_kernel<3, 5, 96><<<gM, 256, 0, stream>>>(hm, mal2f, mar2f, elm, erm, NM);
    aggr_kernel<3, 5, 96><<<gM, 256, 0, stream>>>(hm, elm, erm, off_m, csr_m, gm, NM, 0.01f);
    colstats_kernel<<<64, 96, 0, stream>>>(gm, cb4, cb4 + 256, NM);
    gnorm_apply_kernel<<<64, 96, 0, stream>>>(gm, cb4, cb4 + 256, mg2_gf, mg2_bf, mg2_af, NM);

    // ---- mesh GAT layer 3 (H=2, D=32) + head-mean + node-mean ----
    gemm_kernel<96, 64><<<gTm, 256, 0, stream>>>(gm, mW3f, hm, NM);
    elr_kernel<2, 5, 64><<<gM, 256, 0, stream>>>(hm, mal3f, mar3f, elm, erm, NM);
    aggr_mean_kernel<<<gM, 256, 0, stream>>>(hm, elm, erm, off_m, csr_m, nullptr,
                                             msum, nullptr, NM);
    final_kernel<<<1, 64, 0, stream>>>(msum, mclsf, d_out, flag, NM);

    (void)n_in; (void)out_size; (void)ws_size;
}

// Round 3
// 1198.411 us; speedup vs baseline: 1.3900x; 1.3900x over previous
//
#include <hip/hip_runtime.h>

typedef unsigned short ushort;
typedef unsigned int uint;
typedef __attribute__((ext_vector_type(8))) short short8;
typedef __attribute__((ext_vector_type(4))) float float4v;

#define DEV __device__ __forceinline__

DEV float b2f(ushort u) {
    union { uint i; float f; } v; v.i = ((uint)u) << 16; return v.f;
}
DEV ushort f2b(float f) {
    union { float f; uint i; } v; v.f = f;
    uint x = v.i;
    uint r = x + 0x7fffu + ((x >> 16) & 1u);
    return (ushort)(r >> 16);
}
DEV float leaky(float x, float s) { return x >= 0.f ? x : s * x; }

// ---------------- dtype sniff: 1 = fp32 inputs, 0 = bf16 inputs ----------------
__global__ void sniff_kernel(const ushort* __restrict__ x, int* __restrict__ flag) {
    int lane = threadIdx.x & 63;
    int cnt = 0;
    for (int j = 0; j < 8; j++) {
        ushort u = x[(lane * 8 + j) * 2];
        int e = (u >> 7) & 0xFF;
        if (e >= 100 && e <= 140) cnt++;
    }
#pragma unroll
    for (int m = 1; m < 64; m <<= 1) cnt += __shfl_xor(cnt, m, 64);
    if (threadIdx.x == 0) *flag = (cnt < 256) ? 1 : 0;
}

struct ConvArgs {
    const void* s[36];
    float* d[36];
    int n[36];
};

__global__ __launch_bounds__(256) void convert_kernel(ConvArgs a, const int* __restrict__ flag) {
    int ai = blockIdx.y;
    int n = a.n[ai];
    const void* s = a.s[ai];
    float* d = a.d[ai];
    bool fp32 = (*flag != 0);
    int stride = gridDim.x * blockDim.x;
    for (int i = blockIdx.x * blockDim.x + threadIdx.x; i < n; i += stride)
        d[i] = fp32 ? ((const float*)s)[i] : b2f(((const ushort*)s)[i]);
}

// ---------------- CSR build ----------------
__global__ __launch_bounds__(256) void hist_kernel(const int* __restrict__ dst,
                                                   int* __restrict__ cnt, int E) {
    int stride = gridDim.x * blockDim.x;
    for (int i = blockIdx.x * blockDim.x + threadIdx.x; i < E; i += stride)
        atomicAdd(&cnt[dst[i]], 1);
}

// multi-block exclusive scan: 2048 elements/block
__global__ __launch_bounds__(256) void scan_local(const int* __restrict__ cnt,
                                                  int* __restrict__ off,
                                                  int* __restrict__ bsum, int n) {
    __shared__ int ls[256];
    int b = blockIdx.x, t = threadIdx.x;
    int base = b * 2048 + t * 8;
    int v[8];
    int s = 0;
#pragma unroll
    for (int i = 0; i < 8; i++) {
        int idx = base + i;
        v[i] = idx < n ? cnt[idx] : 0;
        s += v[i];
    }
    ls[t] = s;
    __syncthreads();
#pragma unroll
    for (int d = 1; d < 256; d <<= 1) {
        int add = (t >= d) ? ls[t - d] : 0;
        __syncthreads();
        ls[t] += add;
        __syncthreads();
    }
    int run = ls[t] - s;  // block-local exclusive prefix
#pragma unroll
    for (int i = 0; i < 8; i++) {
        int idx = base + i;
        if (idx < n) off[idx] = run;
        run += v[i];
    }
    if (t == 255) bsum[b] = ls[255];
}

__global__ __launch_bounds__(256) void scan_fixup(const int* __restrict__ bsum,
                                                  int* __restrict__ off, int n) {
    int b = blockIdx.x, t = threadIdx.x;
    int base = 0;
    for (int i = 0; i < b; i++) base += bsum[i];
    int idx0 = b * 2048 + t * 8;
    if (base != 0) {
#pragma unroll
        for (int i = 0; i < 8; i++) {
            int idx = idx0 + i;
            if (idx < n) off[idx] += base;
        }
    }
    if (b == gridDim.x - 1 && t == 255) off[n] = base + bsum[b];
}

__global__ __launch_bounds__(256) void scatter_kernel(const int* __restrict__ src,
                                                      const int* __restrict__ dst,
                                                      const int* __restrict__ off,
                                                      int* __restrict__ cursor,
                                                      int* __restrict__ csr, int E) {
    int stride = gridDim.x * blockDim.x;
    for (int i = blockIdx.x * blockDim.x + threadIdx.x; i < E; i += stride) {
        int d = dst[i];
        int pos = off[d] + atomicAdd(&cursor[d], 1);
        csr[pos] = src[i];
    }
}

// ---------------- layer-1 projection (K=5) + el/er ----------------
__global__ __launch_bounds__(256) void proj1_kernel(const float* __restrict__ x,
                                                    const float* __restrict__ W,
                                                    const float* __restrict__ al,
                                                    const float* __restrict__ ar,
                                                    float* __restrict__ h,
                                                    float* __restrict__ el,
                                                    float* __restrict__ er, int Nn) {
    int t = threadIdx.x;
    int head = t >> 6, lane = t & 63;
    float wv[5];
#pragma unroll
    for (int k = 0; k < 5; k++) wv[k] = W[k * 256 + t];
    float alv = al[t];
    float arv = ar[t];
    int n0 = blockIdx.x * 4;
    int n1 = min(n0 + 4, Nn);
    for (int n = n0; n < n1; n++) {
        float acc = 0.f;
#pragma unroll
        for (int k = 0; k < 5; k++) acc += x[n * 5 + k] * wv[k];
        h[(size_t)n * 256 + t] = acc;
        float pl = acc * alv, pr = acc * arv;
#pragma unroll
        for (int m = 1; m < 64; m <<= 1) {
            pl += __shfl_xor(pl, m, 64);
            pr += __shfl_xor(pr, m, 64);
        }
        if (lane == 0) { el[n * 4 + head] = pl; er[n * 4 + head] = pr; }
    }
}

// ---------------- el/er from projected features ----------------
template <int H, int LOGD, int HD>
__global__ __launch_bounds__(256) void elr_kernel(const float* __restrict__ h,
                                                  const float* __restrict__ al,
                                                  const float* __restrict__ ar,
                                                  float* __restrict__ el,
                                                  float* __restrict__ er, int Nn) {
    int gw = blockIdx.x * 4 + (threadIdx.x >> 6);
    if (gw >= Nn) return;
    int lane = threadIdx.x & 63;
    constexpr int D = 1 << LOGD;
    constexpr int ND = (HD + 63) / 64;
#pragma unroll
    for (int j = 0; j < ND; j++) {
        int d = lane + 64 * j;
        bool valid = d < HD;
        float hv = 0.f, av = 0.f, rv = 0.f;
        if (valid) { hv = h[(size_t)gw * HD + d]; av = al[d]; rv = ar[d]; }
        float pl = hv * av, pr = hv * rv;
#pragma unroll
        for (int m = 1; m < D && m < 64; m <<= 1) {
            pl += __shfl_xor(pl, m, 64);
            pr += __shfl_xor(pr, m, 64);
        }
        int hd = d >> LOGD;
        if (valid && (d & (D - 1)) == 0) { el[gw * H + hd] = pl; er[gw * H + hd] = pr; }
    }
}

// ---------------- GAT edge aggregation (CSR, one wave per dst, U-edge unroll) ----------------
template <int H, int LOGD, int HD, int U>
__global__ __launch_bounds__(256) void aggr_kernel(const float* __restrict__ h,
                                                   const float* __restrict__ el,
                                                   const float* __restrict__ er,
                                                   const int* __restrict__ off,
                                                   const int* __restrict__ csr,
                                                   float* __restrict__ out, int Nn,
                                                   float oslope) {
    int gw = blockIdx.x * 4 + (threadIdx.x >> 6);
    if (gw >= Nn) return;
    int lane = threadIdx.x & 63;
    constexpr int ND = (HD + 63) / 64;
    float acc[ND];
    float s[H], erd[H];
#pragma unroll
    for (int j = 0; j < ND; j++) acc[j] = 0.f;
#pragma unroll
    for (int hh = 0; hh < H; hh++) { s[hh] = 0.f; erd[hh] = er[gw * H + hh]; }
    int e = off[gw], e1 = off[gw + 1];
    for (; e + U <= e1; e += U) {
        int srcs[U];
#pragma unroll
        for (int u = 0; u < U; u++) srcs[u] = csr[e + u];
        float w_[U][H];
#pragma unroll
        for (int u = 0; u < U; u++) {
#pragma unroll
            for (int hh = 0; hh < H; hh++) {
                float ev = el[srcs[u] * H + hh] + erd[hh];
                ev = ev >= 0.f ? ev : 0.2f * ev;
                float wv = __expf(fminf(ev, 80.f));
                w_[u][hh] = wv;
                s[hh] += wv;
            }
        }
#pragma unroll
        for (int j = 0; j < ND; j++) {
            int d = lane + 64 * j;
            if (d < HD) {
#pragma unroll
                for (int u = 0; u < U; u++)
                    acc[j] += w_[u][d >> LOGD] * h[(size_t)srcs[u] * HD + d];
            }
        }
    }
    for (; e < e1; e++) {
        int src = csr[e];
        float w_[H];
#pragma unroll
        for (int hh = 0; hh < H; hh++) {
            float ev = el[src * H + hh] + erd[hh];
            ev = ev >= 0.f ? ev : 0.2f * ev;
            float wv = __expf(fminf(ev, 80.f));
            w_[hh] = wv;
            s[hh] += wv;
        }
#pragma unroll
        for (int j = 0; j < ND; j++) {
            int d = lane + 64 * j;
            if (d < HD) acc[j] += w_[d >> LOGD] * h[(size_t)src * HD + d];
        }
    }
#pragma unroll
    for (int j = 0; j < ND; j++) {
        int d = lane + 64 * j;
        if (d < HD) {
            float v = acc[j] / fmaxf(s[d >> LOGD], 1e-9f);
            out[(size_t)gw * HD + d] = leaky(v, oslope);
        }
    }
}

// final GAT layer: H=2, D=32, HD=64, head-mean + atomic segment-sum, 4-edge unroll
__global__ __launch_bounds__(256) void aggr_mean_kernel(const float* __restrict__ h,
                                                        const float* __restrict__ el,
                                                        const float* __restrict__ er,
                                                        const int* __restrict__ off,
                                                        const int* __restrict__ csr,
                                                        const int* __restrict__ gid,
                                                        float* __restrict__ out_sum,
                                                        float* __restrict__ out_cnt,
                                                        int Nn) {
    int gw = blockIdx.x * 4 + (threadIdx.x >> 6);
    if (gw >= Nn) return;
    int lane = threadIdx.x & 63;
    bool lo32 = lane < 32;
    float erd0 = er[gw * 2], erd1 = er[gw * 2 + 1];
    float acc = 0.f, s0 = 0.f, s1 = 0.f;
    int e = off[gw], e1 = off[gw + 1];
    for (; e + 4 <= e1; e += 4) {
        int srcs[4];
#pragma unroll
        for (int u = 0; u < 4; u++) srcs[u] = csr[e + u];
        float w0[4], w1[4];
#pragma unroll
        for (int u = 0; u < 4; u++) {
            float e0 = el[srcs[u] * 2] + erd0;      e0 = e0 >= 0.f ? e0 : 0.2f * e0;
            float e1v = el[srcs[u] * 2 + 1] + erd1; e1v = e1v >= 0.f ? e1v : 0.2f * e1v;
            w0[u] = __expf(fminf(e0, 80.f));
            w1[u] = __expf(fminf(e1v, 80.f));
            s0 += w0[u]; s1 += w1[u];
        }
#pragma unroll
        for (int u = 0; u < 4; u++)
            acc += (lo32 ? w0[u] : w1[u]) * h[(size_t)srcs[u] * 64 + lane];
    }
    for (; e < e1; e++) {
        int src = csr[e];
        float e0 = el[src * 2] + erd0;      e0 = e0 >= 0.f ? e0 : 0.2f * e0;
        float e1v = el[src * 2 + 1] + erd1; e1v = e1v >= 0.f ? e1v : 0.2f * e1v;
        float w0 = __expf(fminf(e0, 80.f)), w1 = __expf(fminf(e1v, 80.f));
        s0 += w0; s1 += w1;
        acc += (lo32 ? w0 : w1) * h[(size_t)src * 64 + lane];
    }
    float ss = lo32 ? s0 : s1;
    float y = acc / fmaxf(ss, 1e-9f);
    float part = __shfl_xor(y, 32, 64);
    float hm = 0.5f * (y + part);
    if (lo32) {
        int base = gid ? gid[gw] * 32 : 0;
        atomicAdd(&out_sum[base + lane], hm);
    }
    if (lane == 0 && out_cnt) atomicAdd(&out_cnt[gid[gw]], 1.0f);
}

// ---------------- GraphNorm: column stats + finalize (sc/sh) ----------------
__global__ void colstats_kernel(const float* __restrict__ x,
                                float* __restrict__ sum,
                                float* __restrict__ sumsq, int Nn) {
    int C = blockDim.x, c = threadIdx.x;
    float ls = 0.f, lq = 0.f;
    for (int r = blockIdx.x; r < Nn; r += gridDim.x) {
        float v = x[(size_t)r * C + c];
        ls += v; lq += v * v;
    }
    atomicAdd(&sum[c], ls);
    atomicAdd(&sumsq[c], lq);
}

// scsh[0..C) = scale, scsh[512..512+C) = shift
__global__ void gnfin_kernel(const float* __restrict__ sum,
                             const float* __restrict__ sumsq,
                             const float* __restrict__ g,
                             const float* __restrict__ b,
                             const float* __restrict__ a,
                             float* __restrict__ scsh, int C, int Nn) {
    int c = threadIdx.x;
    if (c >= C) return;
    float invn = 1.f / (float)Nn;
    float mu = sum[c] * invn, ex2 = sumsq[c] * invn;
    float av = a[c];
    float var = ex2 - 2.f * av * mu * mu + av * av * mu * mu;
    float sc = g[c] * rsqrtf(var + 1e-5f);
    scsh[c] = sc;
    scsh[512 + c] = b[c] - sc * av * mu;
}

// GraphNorm apply for readout: writes d_out (per flag) + fp32 mesh input
__global__ void gnorm_apply_ro_kernel(const float* __restrict__ x,
                                      const float* __restrict__ sum,
                                      const float* __restrict__ sumsq,
                                      const float* __restrict__ g,
                                      const float* __restrict__ b,
                                      const float* __restrict__ a,
                                      void* __restrict__ doutv,
                                      const int* __restrict__ flag,
                                      float* __restrict__ rof, int Nn) {
    int c = threadIdx.x;  // C = 32
    float invn = 1.f / (float)Nn;
    float mu = sum[c] * invn, ex2 = sumsq[c] * invn;
    float av = a[c];
    float var = ex2 - 2.f * av * mu * mu + av * av * mu * mu;
    float sc = g[c] * rsqrtf(var + 1e-5f);
    float sh = b[c] - sc * av * mu;
    bool fp32 = (*flag != 0);
    for (int r = blockIdx.x; r < Nn; r += gridDim.x) {
        int i = r * 32 + c;
        float v = x[i] * sc + sh;
        rof[i] = v;
        if (fp32) ((float*)doutv)[15 + i] = v;
        else      ((ushort*)doutv)[15 + i] = f2b(v);
    }
}

// ---------------- readout: segment-mean @ pcls + leaky ----------------
__global__ __launch_bounds__(256) void readout_kernel(const float* __restrict__ ro_sum,
                                                      const float* __restrict__ ro_cnt,
                                                      const float* __restrict__ pcls,
                                                      float* __restrict__ ro_lin, int NGc) {
    int idx = blockIdx.x * blockDim.x + threadIdx.x;
    int g = idx >> 5, c = idx & 31;
    if (g >= NGc) return;
    float inv = 1.f / fmaxf(ro_cnt[g], 1.f);
    float acc = 0.f;
#pragma unroll
    for (int k = 0; k < 32; k++) acc += ro_sum[g * 32 + k] * inv * pcls[k * 32 + c];
    ro_lin[g * 32 + c] = leaky(acc, 0.01f);
}

// ---------------- MFMA GEMM: C[M,N] = gnorm(A)[M,K] @ B[K,N] ----------------
template <int K, int N, bool GN>
__global__ __launch_bounds__(256) void gemm_kernel(const float* __restrict__ A,
                                                   const float* __restrict__ B,
                                                   const float* __restrict__ scsh,
                                                   float* __restrict__ C, int M) {
    constexpr int NT = N / 16;
    constexpr int AROW = 40;
    __shared__ __align__(16) ushort Alds[64 * AROW];
    __shared__ __align__(16) ushort Blds[32 * N];  // swizzled [k/8][n][k%8]
    int tid = threadIdx.x;
    int w = tid >> 6, lane = tid & 63, q = lane >> 4, l16 = lane & 15;
    int m0 = blockIdx.x * 64;
    float4v acc[NT];
#pragma unroll
    for (int nt = 0; nt < NT; nt++) acc[nt] = (float4v){0.f, 0.f, 0.f, 0.f};

    for (int kc = 0; kc < K; kc += 32) {
        __syncthreads();
        {  // stage A: 64 rows x 32 k (fp32 -> gnorm -> bf16)
#pragma unroll
            for (int it = 0; it < 2; it++) {
                int idx = it * 256 + tid;
                int r = idx >> 3;
                int c4 = (idx & 7) * 4;
                int gr = m0 + r;
                float4 av = {0.f, 0.f, 0.f, 0.f};
                if (gr < M) av = *(const float4*)(A + (size_t)gr * K + kc + c4);
                if (GN) {
                    float4 s4 = *(const float4*)(scsh + kc + c4);
                    float4 h4 = *(const float4*)(scsh + 512 + kc + c4);
                    av.x = av.x * s4.x + h4.x;
                    av.y = av.y * s4.y + h4.y;
                    av.z = av.z * s4.z + h4.z;
                    av.w = av.w * s4.w + h4.w;
                }
                uint2 pk;
                pk.x = (uint)f2b(av.x) | ((uint)f2b(av.y) << 16);
                pk.y = (uint)f2b(av.z) | ((uint)f2b(av.w) << 16);
                *(uint2*)(&Alds[r * AROW + c4]) = pk;
            }
        }
        {  // stage B swizzled (fp32 -> bf16)
            constexpr int PAIRS = 16 * N;
#pragma unroll
            for (int p0 = 0; p0 < PAIRS; p0 += 256) {
                int p = p0 + tid;
                int k_ = p / (N / 2);
                int n0 = (p % (N / 2)) * 2;
                float2 bv = *(const float2*)(B + (size_t)(kc + k_) * N + n0);
                int base = (((k_ >> 3) * N + n0) << 3) + (k_ & 7);
                Blds[base] = f2b(bv.x);
                Blds[base + 8] = f2b(bv.y);
            }
        }
        __syncthreads();
        short8 a = *(const short8*)(&Alds[(w * 16 + l16) * AROW + q * 8]);
#pragma unroll
        for (int nt = 0; nt < NT; nt++) {
            short8 b = *(const short8*)(&Blds[(q * N + nt * 16 + l16) * 8]);
            acc[nt] = __builtin_amdgcn_mfma_f32_16x16x32_bf16(a, b, acc[nt], 0, 0, 0);
        }
    }
#pragma unroll
    for (int nt = 0; nt < NT; nt++) {
#pragma unroll
        for (int i = 0; i < 4; i++) {
            int row = m0 + w * 16 + q * 4 + i;
            if (row < M) C[(size_t)row * N + nt * 16 + l16] = acc[nt][i];
        }
    }
}

// ---------------- final: node-mean @ mcls ----------------
__global__ __launch_bounds__(64) void final_kernel(const float* __restrict__ msum,
                                                   const float* __restrict__ mcls,
                                                   void* __restrict__ doutv,
                                                   const int* __restrict__ flag, int Nm) {
    int t = threadIdx.x;
    if (t < 15) {
        float inv = 1.f / (float)Nm;
        float acc = 0.f;
#pragma unroll
        for (int c = 0; c < 32; c++) acc += msum[c] * inv * mcls[c * 15 + t];
        if (*flag) ((float*)doutv)[t] = acc;
        else       ((ushort*)doutv)[t] = f2b(acc);
    }
}

extern "C" void kernel_launch(void* const* d_in, const int* in_sizes, int n_in,
                              void* d_out, int out_size, void* d_ws, size_t ws_size,
                              hipStream_t stream) {
    const int NP = 100000, NG = 2000, EP = 800000, NM = 2000, EM = 32000;

    const int* patch_src = (const int*)d_in[1];
    const int* patch_dst = (const int*)d_in[2];
    const int* patch_gid = (const int*)d_in[3];
    const int* mesh_src = (const int*)d_in[4];
    const int* mesh_dst = (const int*)d_in[5];

    // ---- workspace carve (256B aligned) ----
    char* p = (char*)d_ws;
    auto alloc = [&](size_t bytes) -> char* {
        char* r = p;
        p += (bytes + 255) & ~(size_t)255;
        return r;
    };
    char* zbase = p;  // zero-initialized region (one memset)
    int* cnt_p = (int*)alloc((size_t)NP * 4);
    int* cursor_p = (int*)alloc((size_t)NP * 4);
    int* cnt_m = (int*)alloc((size_t)NM * 4);
    int* cursor_m = (int*)alloc((size_t)NM * 4);
    float* ro_sum = (float*)alloc((size_t)NG * 32 * 4);
    float* ro_cnt = (float*)alloc((size_t)NG * 4);
    float* msum = (float*)alloc(32 * 4);
    float* colbuf = (float*)alloc(6 * 512 * 4);
    size_t zbytes = (size_t)(p - zbase);
    int* flag = (int*)alloc(256);
    int* off_p = (int*)alloc((size_t)(NP + 1) * 4);
    int* off_m = (int*)alloc((size_t)(NM + 1) * 4);
    int* bsum_p = (int*)alloc(64 * 4);
    int* bsum_m = (int*)alloc(16 * 4);
    int* csr_p = (int*)alloc((size_t)EP * 4);
    int* csr_m = (int*)alloc((size_t)EM * 4);
    float* el = (float*)alloc((size_t)NP * 4 * 4);
    float* er = (float*)alloc((size_t)NP * 4 * 4);
    float* hbuf = (float*)alloc((size_t)NP * 256 * 4);
    float* gbuf = (float*)alloc((size_t)NP * 256 * 4);
    float* hm = (float*)alloc((size_t)NM * 256 * 4);
    float* gm = (float*)alloc((size_t)NM * 256 * 4);
    float* elm = (float*)alloc((size_t)NM * 4 * 4);
    float* erm = (float*)alloc((size_t)NM * 4 * 4);
    float* ro_lin = (float*)alloc((size_t)NG * 32 * 4);
    float* ro_f = (float*)alloc((size_t)NG * 32 * 4);
    float* scsh0 = (float*)alloc(1024 * 4);
    float* scsh1 = (float*)alloc(1024 * 4);
    float* scsh3 = (float*)alloc(1024 * 4);
    float* scsh4 = (float*)alloc(1024 * 4);

    // converted fp32 copies of all float inputs
    ConvArgs ca;
    float* convp[36];
    int conv_idx[36];
    conv_idx[0] = 0;
    for (int i = 1; i < 36; i++) conv_idx[i] = 5 + i;  // inputs 6..40
    for (int j = 0; j < 36; j++) {
        int ii = conv_idx[j];
        int n = in_sizes[ii];
        float* dd = (float*)alloc((size_t)n * 4);
        ca.s[j] = d_in[ii];
        ca.d[j] = dd;
        ca.n[j] = n;
        convp[j] = dd;
    }
    const float* xf = convp[0];
    const float *pW1f = convp[1], *pal1f = convp[2], *par1f = convp[3];
    const float *pg1_gf = convp[4], *pg1_bf = convp[5], *pg1_af = convp[6];
    const float *pW2f = convp[7], *pal2f = convp[8], *par2f = convp[9];
    const float *pg2_gf = convp[10], *pg2_bf = convp[11], *pg2_af = convp[12];
    const float *pW3f = convp[13], *pal3f = convp[14], *par3f = convp[15];
    const float* pclsf = convp[16];
    const float *rn_gf = convp[17], *rn_bf2 = convp[18], *rn_af = convp[19];
    const float *mW1f = convp[20], *mal1f = convp[21], *mar1f = convp[22];
    const float *mg1_gf = convp[23], *mg1_bf = convp[24], *mg1_af = convp[25];
    const float *mW2f = convp[26], *mal2f = convp[27], *mar2f = convp[28];
    const float *mg2_gf = convp[29], *mg2_bf = convp[30], *mg2_af = convp[31];
    const float *mW3f = convp[32], *mal3f = convp[33], *mar3f = convp[34];
    const float* mclsf = convp[35];

    hipMemsetAsync(zbase, 0, zbytes, stream);
    sniff_kernel<<<1, 64, 0, stream>>>((const ushort*)d_in[0], flag);
    convert_kernel<<<dim3(16, 36), 256, 0, stream>>>(ca, flag);

    // ---- CSR build (patch + mesh) ----
    const int SBP = (NP + 2047) / 2048, SBM = (NM + 2047) / 2048;
    hist_kernel<<<512, 256, 0, stream>>>(patch_dst, cnt_p, EP);
    hist_kernel<<<64, 256, 0, stream>>>(mesh_dst, cnt_m, EM);
    scan_local<<<SBP, 256, 0, stream>>>(cnt_p, off_p, bsum_p, NP);
    scan_fixup<<<SBP, 256, 0, stream>>>(bsum_p, off_p, NP);
    scan_local<<<SBM, 256, 0, stream>>>(cnt_m, off_m, bsum_m, NM);
    scan_fixup<<<SBM, 256, 0, stream>>>(bsum_m, off_m, NM);
    scatter_kernel<<<512, 256, 0, stream>>>(patch_src, patch_dst, off_p, cursor_p, csr_p, EP);
    scatter_kernel<<<64, 256, 0, stream>>>(mesh_src, mesh_dst, off_m, cursor_m, csr_m, EM);

    int gP = (NP + 3) / 4, gM = (NM + 3) / 4;
    int gT = (NP + 63) / 64, gTm = (NM + 63) / 64;
    float* cb0 = colbuf + 0 * 512;
    float* cb1 = colbuf + 1 * 512;
    float* cb2 = colbuf + 2 * 512;
    float* cb3 = colbuf + 3 * 512;
    float* cb4 = colbuf + 4 * 512;

    // ---- patch GAT layer 1 (H=4, D=64) ----
    proj1_kernel<<<gP, 256, 0, stream>>>(xf, pW1f, pal1f, par1f, hbuf, el, er, NP);
    aggr_kernel<4, 6, 256, 2><<<gP, 256, 0, stream>>>(hbuf, el, er, off_p, csr_p, gbuf, NP, 0.01f);
    colstats_kernel<<<256, 256, 0, stream>>>(gbuf, cb0, cb0 + 256, NP);
    gnfin_kernel<<<1, 256, 0, stream>>>(cb0, cb0 + 256, pg1_gf, pg1_bf, pg1_af, scsh0, 256, NP);

    // ---- patch GAT layer 2 (H=3, D=64) ----
    gemm_kernel<256, 192, true><<<gT, 256, 0, stream>>>(gbuf, pW2f, scsh0, hbuf, NP);
    elr_kernel<3, 6, 192><<<gP, 256, 0, stream>>>(hbuf, pal2f, par2f, el, er, NP);
    aggr_kernel<3, 6, 192, 2><<<gP, 256, 0, stream>>>(hbuf, el, er, off_p, csr_p, gbuf, NP, 0.01f);
    colstats_kernel<<<256, 192, 0, stream>>>(gbuf, cb1, cb1 + 256, NP);
    gnfin_kernel<<<1, 256, 0, stream>>>(cb1, cb1 + 256, pg2_gf, pg2_bf, pg2_af, scsh1, 192, NP);

    // ---- patch GAT layer 3 (H=2, D=32) + head-mean + segment readout ----
    gemm_kernel<192, 64, true><<<gT, 256, 0, stream>>>(gbuf, pW3f, scsh1, hbuf, NP);
    elr_kernel<2, 5, 64><<<gP, 256, 0, stream>>>(hbuf, pal3f, par3f, el, er, NP);
    aggr_mean_kernel<<<gP, 256, 0, stream>>>(hbuf, el, er, off_p, csr_p, patch_gid,
                                             ro_sum, ro_cnt, NP);

    // ---- readout: mean -> @pcls -> leaky -> GraphNorm (output 1 + mesh input) ----
    readout_kernel<<<(NG * 32 + 255) / 256, 256, 0, stream>>>(ro_sum, ro_cnt, pclsf, ro_lin, NG);
    colstats_kernel<<<64, 32, 0, stream>>>(ro_lin, cb2, cb2 + 256, NG);
    gnorm_apply_ro_kernel<<<64, 32, 0, stream>>>(ro_lin, cb2, cb2 + 256, rn_gf, rn_bf2, rn_af,
                                                 d_out, flag, ro_f, NG);

    // ---- mesh GAT layer 1 (H=4, D=64) ----
    gemm_kernel<32, 256, false><<<gTm, 256, 0, stream>>>(ro_f, mW1f, nullptr, hm, NM);
    elr_kernel<4, 6, 256><<<gM, 256, 0, stream>>>(hm, mal1f, mar1f, elm, erm, NM);
    aggr_kernel<4, 6, 256, 2><<<gM, 256, 0, stream>>>(hm, elm, erm, off_m, csr_m, gm, NM, 0.01f);
    colstats_kernel<<<64, 256, 0, stream>>>(gm, cb3, cb3 + 256, NM);
    gnfin_kernel<<<1, 256, 0, stream>>>(cb3, cb3 + 256, mg1_gf, mg1_bf, mg1_af, scsh3, 256, NM);

    // ---- mesh GAT layer 2 (H=3, D=32) ----
    gemm_kernel<256, 96, true><<<gTm, 256, 0, stream>>>(gm, mW2f, scsh3, hm, NM);
    elr_kernel<3, 5, 96><<<gM, 256, 0, stream>>>(hm, mal2f, mar2f, elm, erm, NM);
    aggr_kernel<3, 5, 96, 4><<<gM, 256, 0, stream>>>(hm, elm, erm, off_m, csr_m, gm, NM, 0.01f);
    colstats_kernel<<<64, 96, 0, stream>>>(gm, cb4, cb4 + 256, NM);
    gnfin_kernel<<<1, 256, 0, stream>>>(cb4, cb4 + 256, mg2_gf, mg2_bf, mg2_af, scsh4, 96, NM);

    // ---- mesh GAT layer 3 (H=2, D=32) + head-mean + node-mean ----
    gemm_kernel<96, 64, true><<<gTm, 256, 0, stream>>>(gm, mW3f, scsh4, hm, NM);
    elr_kernel<2, 5, 64><<<gM, 256, 0, stream>>>(hm, mal3f, mar3f, elm, erm, NM);
    aggr_mean_kernel<<<gM, 256, 0, stream>>>(hm, elm, erm, off_m, csr_m, nullptr,
                                             msum, nullptr, NM);
    final_kernel<<<1, 64, 0, stream>>>(msum, mclsf, d_out, flag, NM);

    (void)n_in; (void)out_size; (void)ws_size;
}

// Round 4
// 1100.873 us; speedup vs baseline: 1.5132x; 1.0886x over previous
//
#include <hip/hip_runtime.h>

typedef unsigned short ushort;
typedef unsigned int uint;
typedef __attribute__((ext_vector_type(8))) short short8;
typedef __attribute__((ext_vector_type(4))) float float4v;

#define DEV __device__ __forceinline__

DEV float b2f(ushort u) {
    union { uint i; float f; } v; v.i = ((uint)u) << 16; return v.f;
}
DEV ushort f2b(float f) {
    union { float f; uint i; } v; v.f = f;
    uint x = v.i;
    uint r = x + 0x7fffu + ((x >> 16) & 1u);
    return (ushort)(r >> 16);
}
DEV float leaky(float x, float s) { return x >= 0.f ? x : s * x; }

// ---------------- convert (+local sniff, +zero slice, +flag write) ----------------
struct ConvArgs {
    const void* s[37];
    float* d[37];
    int n[37];
};

__global__ __launch_bounds__(256) void convert_kernel(ConvArgs a, const ushort* __restrict__ x0,
                                                      int* __restrict__ flag) {
    __shared__ int sfp32;
    int tid = threadIdx.x;
    // local sniff of d_in[0] (all blocks compute the same value)
    if (tid < 64) {
        int cnt = 0;
        for (int j = 0; j < 8; j++) {
            ushort u = x0[(tid * 8 + j) * 2];
            int e = (u >> 7) & 0xFF;
            if (e >= 100 && e <= 140) cnt++;
        }
#pragma unroll
        for (int m = 1; m < 64; m <<= 1) cnt += __shfl_xor(cnt, m, 64);
        if (tid == 0) sfp32 = (cnt < 256) ? 1 : 0;
    }
    __syncthreads();
    bool fp32 = (sfp32 != 0);
    if (blockIdx.x == 0 && blockIdx.y == 0 && tid == 0) *flag = fp32 ? 1 : 0;

    int ai = blockIdx.y;
    int n = a.n[ai];
    const void* s = a.s[ai];
    float* d = a.d[ai];
    int stride = gridDim.x * blockDim.x;
    if (s == nullptr) {  // zero slice
        for (int i = blockIdx.x * blockDim.x + tid; i < n; i += stride) d[i] = 0.f;
    } else {
        for (int i = blockIdx.x * blockDim.x + tid; i < n; i += stride)
            d[i] = fp32 ? ((const float*)s)[i] : b2f(((const ushort*)s)[i]);
    }
}

// ---------------- CSR build (patch+mesh merged) ----------------
__global__ __launch_bounds__(256) void hist_both(const int* __restrict__ dstP, int* __restrict__ cntP, int EPc,
                                                 const int* __restrict__ dstM, int* __restrict__ cntM, int EMc,
                                                 int PB) {
    bool patch = (int)blockIdx.x < PB;
    const int* dst = patch ? dstP : dstM;
    int* cnt = patch ? cntP : cntM;
    int E = patch ? EPc : EMc;
    int nb = patch ? PB : gridDim.x - PB;
    int b = patch ? blockIdx.x : blockIdx.x - PB;
    int stride = nb * blockDim.x;
    for (int i = b * blockDim.x + threadIdx.x; i < E; i += stride)
        atomicAdd(&cnt[dst[i]], 1);
}

// multi-block exclusive scan: 2048 elements/block
__global__ __launch_bounds__(256) void scan_both(const int* __restrict__ cntP, int* __restrict__ offP,
                                                 int* __restrict__ bsumP, int nP, int SBP,
                                                 const int* __restrict__ cntM, int* __restrict__ offM,
                                                 int* __restrict__ bsumM, int nM) {
    __shared__ int ls[256];
    bool patch = (int)blockIdx.x < SBP;
    const int* cnt = patch ? cntP : cntM;
    int* off = patch ? offP : offM;
    int* bsum = patch ? bsumP : bsumM;
    int n = patch ? nP : nM;
    int b = patch ? blockIdx.x : blockIdx.x - SBP;
    int t = threadIdx.x;
    int base = b * 2048 + t * 8;
    int v[8];
    int s = 0;
#pragma unroll
    for (int i = 0; i < 8; i++) {
        int idx = base + i;
        v[i] = idx < n ? cnt[idx] : 0;
        s += v[i];
    }
    ls[t] = s;
    __syncthreads();
#pragma unroll
    for (int d = 1; d < 256; d <<= 1) {
        int add = (t >= d) ? ls[t - d] : 0;
        __syncthreads();
        ls[t] += add;
        __syncthreads();
    }
    int run = ls[t] - s;
#pragma unroll
    for (int i = 0; i < 8; i++) {
        int idx = base + i;
        if (idx < n) off[idx] = run;
        run += v[i];
    }
    if (t == 255) bsum[b] = ls[255];
}

__global__ __launch_bounds__(256) void fixup_both(const int* __restrict__ bsumP, int* __restrict__ offP,
                                                  int nP, int SBP,
                                                  const int* __restrict__ bsumM, int* __restrict__ offM,
                                                  int nM, int SBM) {
    bool patch = (int)blockIdx.x < SBP;
    const int* bsum = patch ? bsumP : bsumM;
    int* off = patch ? offP : offM;
    int n = patch ? nP : nM;
    int nb = patch ? SBP : SBM;
    int b = patch ? blockIdx.x : blockIdx.x - SBP;
    int t = threadIdx.x;
    int base = 0;
    for (int i = 0; i < b; i++) base += bsum[i];
    int idx0 = b * 2048 + t * 8;
    if (base != 0) {
#pragma unroll
        for (int i = 0; i < 8; i++) {
            int idx = idx0 + i;
            if (idx < n) off[idx] += base;
        }
    }
    if (b == nb - 1 && t == 255) off[n] = base + bsum[b];
}

__global__ __launch_bounds__(256) void scatter_both(const int* __restrict__ srcP, const int* __restrict__ dstP,
                                                    const int* __restrict__ offP, int* __restrict__ curP,
                                                    int* __restrict__ csrP, int EPc,
                                                    const int* __restrict__ srcM, const int* __restrict__ dstM,
                                                    const int* __restrict__ offM, int* __restrict__ curM,
                                                    int* __restrict__ csrM, int EMc, int PB) {
    bool patch = (int)blockIdx.x < PB;
    const int* src = patch ? srcP : srcM;
    const int* dst = patch ? dstP : dstM;
    const int* off = patch ? offP : offM;
    int* cursor = patch ? curP : curM;
    int* csr = patch ? csrP : csrM;
    int E = patch ? EPc : EMc;
    int nb = patch ? PB : gridDim.x - PB;
    int b = patch ? blockIdx.x : blockIdx.x - PB;
    int stride = nb * blockDim.x;
    for (int i = b * blockDim.x + threadIdx.x; i < E; i += stride) {
        int d = dst[i];
        int pos = off[d] + atomicAdd(&cursor[d], 1);
        csr[pos] = src[i];
    }
}

// ---------------- layer-1: el/er only (h recomputed on the fly in aggr1) ----------------
__global__ __launch_bounds__(256) void proj1_elr_kernel(const float* __restrict__ x,
                                                        const float* __restrict__ W,
                                                        const float* __restrict__ al,
                                                        const float* __restrict__ ar,
                                                        float* __restrict__ el,
                                                        float* __restrict__ er, int Nn) {
    int t = threadIdx.x;
    int head = t >> 6, lane = t & 63;
    float wv[5];
#pragma unroll
    for (int k = 0; k < 5; k++) wv[k] = W[k * 256 + t];
    float alv = al[t];
    float arv = ar[t];
    int n0 = blockIdx.x * 4;
    int n1 = min(n0 + 4, Nn);
    for (int n = n0; n < n1; n++) {
        float acc = 0.f;
#pragma unroll
        for (int k = 0; k < 5; k++) acc += x[n * 5 + k] * wv[k];
        float pl = acc * alv, pr = acc * arv;
#pragma unroll
        for (int m = 1; m < 64; m <<= 1) {
            pl += __shfl_xor(pl, m, 64);
            pr += __shfl_xor(pr, m, 64);
        }
        if (lane == 0) { el[n * 4 + head] = pl; er[n * 4 + head] = pr; }
    }
}

// ---------------- patch layer-1 aggregation with on-the-fly h (K=5, HD=256, H=4) ----------------
__global__ __launch_bounds__(256) void aggr1_fly_kernel(const float* __restrict__ x,
                                                        const float* __restrict__ W,
                                                        const float* __restrict__ el,
                                                        const float* __restrict__ er,
                                                        const int* __restrict__ off,
                                                        const int* __restrict__ csr,
                                                        float* __restrict__ out, int Nn) {
    int gw = blockIdx.x * 4 + (threadIdx.x >> 6);
    if (gw >= Nn) return;
    int lane = threadIdx.x & 63;
    int c0 = lane * 4;
    int myhead = lane >> 4;  // (lane*4)>>6
    float w0[5], w1[5], w2[5], w3[5];
#pragma unroll
    for (int k = 0; k < 5; k++) {
        float4 wv = *(const float4*)(W + k * 256 + c0);
        w0[k] = wv.x; w1[k] = wv.y; w2[k] = wv.z; w3[k] = wv.w;
    }
    float erd = er[gw * 4 + myhead];
    float a0 = 0.f, a1 = 0.f, a2 = 0.f, a3 = 0.f, s = 0.f;
    int e = off[gw], e1 = off[gw + 1];
    for (; e + 2 <= e1; e += 2) {
        int sA = csr[e], sB = csr[e + 1];
        float xA[5], xB[5];
#pragma unroll
        for (int k = 0; k < 5; k++) { xA[k] = x[sA * 5 + k]; xB[k] = x[sB * 5 + k]; }
        float evA = el[sA * 4 + myhead] + erd;
        float evB = el[sB * 4 + myhead] + erd;
        evA = evA >= 0.f ? evA : 0.2f * evA;
        evB = evB >= 0.f ? evB : 0.2f * evB;
        float wA = __expf(fminf(evA, 80.f));
        float wB = __expf(fminf(evB, 80.f));
        float hA0 = 0.f, hA1 = 0.f, hA2 = 0.f, hA3 = 0.f;
        float hB0 = 0.f, hB1 = 0.f, hB2 = 0.f, hB3 = 0.f;
#pragma unroll
        for (int k = 0; k < 5; k++) {
            hA0 += xA[k] * w0[k]; hA1 += xA[k] * w1[k];
            hA2 += xA[k] * w2[k]; hA3 += xA[k] * w3[k];
            hB0 += xB[k] * w0[k]; hB1 += xB[k] * w1[k];
            hB2 += xB[k] * w2[k]; hB3 += xB[k] * w3[k];
        }
        a0 += wA * hA0 + wB * hB0;
        a1 += wA * hA1 + wB * hB1;
        a2 += wA * hA2 + wB * hB2;
        a3 += wA * hA3 + wB * hB3;
        s += wA + wB;
    }
    for (; e < e1; e++) {
        int sA = csr[e];
        float xA[5];
#pragma unroll
        for (int k = 0; k < 5; k++) xA[k] = x[sA * 5 + k];
        float evA = el[sA * 4 + myhead] + erd;
        evA = evA >= 0.f ? evA : 0.2f * evA;
        float wA = __expf(fminf(evA, 80.f));
        float hA0 = 0.f, hA1 = 0.f, hA2 = 0.f, hA3 = 0.f;
#pragma unroll
        for (int k = 0; k < 5; k++) {
            hA0 += xA[k] * w0[k]; hA1 += xA[k] * w1[k];
            hA2 += xA[k] * w2[k]; hA3 += xA[k] * w3[k];
        }
        a0 += wA * hA0; a1 += wA * hA1; a2 += wA * hA2; a3 += wA * hA3;
        s += wA;
    }
    float inv = 1.f / fmaxf(s, 1e-9f);
    float4 o;
    o.x = leaky(a0 * inv, 0.01f);
    o.y = leaky(a1 * inv, 0.01f);
    o.z = leaky(a2 * inv, 0.01f);
    o.w = leaky(a3 * inv, 0.01f);
    *(float4*)(out + (size_t)gw * 256 + c0) = o;
}

// ---------------- gather aggregation (float4/lane, 1 exp/lane) ----------------
template <int H, int LOGD, int HD, int U>
__global__ __launch_bounds__(256) void aggr4_kernel(const float* __restrict__ h,
                                                    const float* __restrict__ el,
                                                    const float* __restrict__ er,
                                                    const int* __restrict__ off,
                                                    const int* __restrict__ csr,
                                                    float* __restrict__ out, int Nn,
                                                    float oslope) {
    int gw = blockIdx.x * 4 + (threadIdx.x >> 6);
    if (gw >= Nn) return;
    int lane = threadIdx.x & 63;
    constexpr int NL = HD / 4;
    bool act = lane < NL;
    int myhead = (lane * 4) >> LOGD;
    float erd = act ? er[gw * H + myhead] : 0.f;
    float a0 = 0.f, a1 = 0.f, a2 = 0.f, a3 = 0.f, s = 0.f;
    int e = off[gw], e1 = off[gw + 1];
    for (; e + U <= e1; e += U) {
        int srcs[U];
#pragma unroll
        for (int u = 0; u < U; u++) srcs[u] = csr[e + u];
        float w[U];
        float4 hv[U];
#pragma unroll
        for (int u = 0; u < U; u++) {
            float ev = act ? el[srcs[u] * H + myhead] + erd : 0.f;
            ev = ev >= 0.f ? ev : 0.2f * ev;
            w[u] = __expf(fminf(ev, 80.f));
            hv[u] = act ? *(const float4*)(h + (size_t)srcs[u] * HD + lane * 4)
                        : make_float4(0.f, 0.f, 0.f, 0.f);
        }
#pragma unroll
        for (int u = 0; u < U; u++) {
            a0 += w[u] * hv[u].x; a1 += w[u] * hv[u].y;
            a2 += w[u] * hv[u].z; a3 += w[u] * hv[u].w;
            s += w[u];
        }
    }
    for (; e < e1; e++) {
        int src = csr[e];
        float ev = act ? el[src * H + myhead] + erd : 0.f;
        ev = ev >= 0.f ? ev : 0.2f * ev;
        float w = __expf(fminf(ev, 80.f));
        float4 hv = act ? *(const float4*)(h + (size_t)src * HD + lane * 4)
                        : make_float4(0.f, 0.f, 0.f, 0.f);
        a0 += w * hv.x; a1 += w * hv.y; a2 += w * hv.z; a3 += w * hv.w;
        s += w;
    }
    if (act) {
        float inv = 1.f / fmaxf(s, 1e-9f);
        float4 o;
        o.x = leaky(a0 * inv, oslope);
        o.y = leaky(a1 * inv, oslope);
        o.z = leaky(a2 * inv, oslope);
        o.w = leaky(a3 * inv, oslope);
        *(float4*)(out + (size_t)gw * HD + lane * 4) = o;
    }
}

// final GAT layer: H=2, D=32, HD=64, head-mean + atomic segment-sum, 8-edge unroll
__global__ __launch_bounds__(256) void aggr_mean_kernel(const float* __restrict__ h,
                                                        const float* __restrict__ el,
                                                        const float* __restrict__ er,
                                                        const int* __restrict__ off,
                                                        const int* __restrict__ csr,
                                                        const int* __restrict__ gid,
                                                        float* __restrict__ out_sum,
                                                        float* __restrict__ out_cnt,
                                                        int Nn) {
    int gw = blockIdx.x * 4 + (threadIdx.x >> 6);
    if (gw >= Nn) return;
    int lane = threadIdx.x & 63;
    bool lo32 = lane < 32;
    float erd = lo32 ? er[gw * 2] : er[gw * 2 + 1];
    float acc = 0.f, s = 0.f;
    int e = off[gw], e1 = off[gw + 1];
    for (; e + 8 <= e1; e += 8) {
        int srcs[8];
#pragma unroll
        for (int u = 0; u < 8; u++) srcs[u] = csr[e + u];
        float w[8], hv[8];
#pragma unroll
        for (int u = 0; u < 8; u++) {
            float2 e2 = *(const float2*)(el + srcs[u] * 2);
            float ev = (lo32 ? e2.x : e2.y) + erd;
            ev = ev >= 0.f ? ev : 0.2f * ev;
            w[u] = __expf(fminf(ev, 80.f));
            hv[u] = h[(size_t)srcs[u] * 64 + lane];
        }
#pragma unroll
        for (int u = 0; u < 8; u++) { acc += w[u] * hv[u]; s += w[u]; }
    }
    for (; e < e1; e++) {
        int src = csr[e];
        float2 e2 = *(const float2*)(el + src * 2);
        float ev = (lo32 ? e2.x : e2.y) + erd;
        ev = ev >= 0.f ? ev : 0.2f * ev;
        float w = __expf(fminf(ev, 80.f));
        acc += w * h[(size_t)src * 64 + lane];
        s += w;
    }
    float y = acc / fmaxf(s, 1e-9f);
    float part = __shfl_xor(y, 32, 64);
    float hm = 0.5f * (y + part);
    if (lo32) {
        int base = gid ? gid[gw] * 32 : 0;
        atomicAdd(&out_sum[base + lane], hm);
    }
    if (lane == 0 && out_cnt) atomicAdd(&out_cnt[gid[gw]], 1.0f);
}

// ---------------- GraphNorm column stats ----------------
__global__ void colstats_kernel(const float* __restrict__ x,
                                float* __restrict__ sum,
                                float* __restrict__ sumsq, int Nn) {
    int C = blockDim.x, c = threadIdx.x;
    float ls = 0.f, lq = 0.f;
    for (int r = blockIdx.x; r < Nn; r += gridDim.x) {
        float v = x[(size_t)r * C + c];
        ls += v; lq += v * v;
    }
    atomicAdd(&sum[c], ls);
    atomicAdd(&sumsq[c], lq);
}

// GraphNorm apply for readout: writes d_out (per flag) + fp32 mesh input
__global__ void gnorm_apply_ro_kernel(const float* __restrict__ x,
                                      const float* __restrict__ sum,
                                      const float* __restrict__ sumsq,
                                      const float* __restrict__ g,
                                      const float* __restrict__ b,
                                      const float* __restrict__ a,
                                      void* __restrict__ doutv,
                                      const int* __restrict__ flag,
                                      float* __restrict__ rof, int Nn) {
    int c = threadIdx.x;  // C = 32
    float invn = 1.f / (float)Nn;
    float mu = sum[c] * invn, ex2 = sumsq[c] * invn;
    float av = a[c];
    float var = ex2 - 2.f * av * mu * mu + av * av * mu * mu;
    float sc = g[c] * rsqrtf(var + 1e-5f);
    float sh = b[c] - sc * av * mu;
    bool fp32 = (*flag != 0);
    for (int r = blockIdx.x; r < Nn; r += gridDim.x) {
        int i = r * 32 + c;
        float v = x[i] * sc + sh;
        rof[i] = v;
        if (fp32) ((float*)doutv)[15 + i] = v;
        else      ((ushort*)doutv)[15 + i] = f2b(v);
    }
}

// ---------------- readout: segment-mean @ pcls + leaky ----------------
__global__ __launch_bounds__(256) void readout_kernel(const float* __restrict__ ro_sum,
                                                      const float* __restrict__ ro_cnt,
                                                      const float* __restrict__ pcls,
                                                      float* __restrict__ ro_lin, int NGc) {
    int idx = blockIdx.x * blockDim.x + threadIdx.x;
    int g = idx >> 5, c = idx & 31;
    if (g >= NGc) return;
    float inv = 1.f / fmaxf(ro_cnt[g], 1.f);
    float acc = 0.f;
#pragma unroll
    for (int k = 0; k < 32; k++) acc += ro_sum[g * 32 + k] * inv * pcls[k * 32 + c];
    ro_lin[g * 32 + c] = leaky(acc, 0.01f);
}

// ---------------- MFMA GEMM: C = gnorm(A) @ B, fused gnfin (prologue) + elr (epilogue) ----------------
template <int K, int N, int H, int LOGD, bool GN>
__global__ __launch_bounds__(256) void gemm_kernel(const float* __restrict__ A,
                                                   const float* __restrict__ B,
                                                   const float* __restrict__ csum,
                                                   const float* __restrict__ g,
                                                   const float* __restrict__ gb,
                                                   const float* __restrict__ ga,
                                                   const float* __restrict__ al,
                                                   const float* __restrict__ ar,
                                                   float* __restrict__ C,
                                                   float* __restrict__ el,
                                                   float* __restrict__ er, int M) {
    constexpr int NT = N / 16;
    constexpr int AROW = 40;
    __shared__ __align__(16) ushort Alds[64 * AROW];
    __shared__ __align__(16) ushort Blds[32 * N];  // swizzled [k/8][n][k%8]
    __shared__ float ScL[256], ShL[256];
    int tid = threadIdx.x;
    int w = tid >> 6, lane = tid & 63, q = lane >> 4, l16 = lane & 15;
    int m0 = blockIdx.x * 64;
    if (GN && tid < K) {
        float invn = 1.f / (float)M;
        float mu = csum[tid] * invn, ex2 = csum[512 + tid] * invn;
        float av = ga[tid];
        float var = ex2 - 2.f * av * mu * mu + av * av * mu * mu;
        float sc = g[tid] * rsqrtf(var + 1e-5f);
        ScL[tid] = sc;
        ShL[tid] = gb[tid] - sc * av * mu;
    }
    float4v acc[NT];
#pragma unroll
    for (int nt = 0; nt < NT; nt++) acc[nt] = (float4v){0.f, 0.f, 0.f, 0.f};

    for (int kc = 0; kc < K; kc += 32) {
        __syncthreads();
        {  // stage A: 64 rows x 32 k (fp32 -> gnorm -> bf16)
#pragma unroll
            for (int it = 0; it < 2; it++) {
                int idx = it * 256 + tid;
                int r = idx >> 3;
                int c4 = (idx & 7) * 4;
                int gr = m0 + r;
                float4 av = {0.f, 0.f, 0.f, 0.f};
                if (gr < M) av = *(const float4*)(A + (size_t)gr * K + kc + c4);
                if (GN) {
                    av.x = av.x * ScL[kc + c4] + ShL[kc + c4];
                    av.y = av.y * ScL[kc + c4 + 1] + ShL[kc + c4 + 1];
                    av.z = av.z * ScL[kc + c4 + 2] + ShL[kc + c4 + 2];
                    av.w = av.w * ScL[kc + c4 + 3] + ShL[kc + c4 + 3];
                }
                uint2 pk;
                pk.x = (uint)f2b(av.x) | ((uint)f2b(av.y) << 16);
                pk.y = (uint)f2b(av.z) | ((uint)f2b(av.w) << 16);
                *(uint2*)(&Alds[r * AROW + c4]) = pk;
            }
        }
        {  // stage B swizzled (fp32 -> bf16)
            constexpr int PAIRS = 16 * N;
#pragma unroll
            for (int p0 = 0; p0 < PAIRS; p0 += 256) {
                int p = p0 + tid;
                int k_ = p / (N / 2);
                int n0 = (p % (N / 2)) * 2;
                float2 bv = *(const float2*)(B + (size_t)(kc + k_) * N + n0);
                int base = (((k_ >> 3) * N + n0) << 3) + (k_ & 7);
                Blds[base] = f2b(bv.x);
                Blds[base + 8] = f2b(bv.y);
            }
        }
        __syncthreads();
        short8 a = *(const short8*)(&Alds[(w * 16 + l16) * AROW + q * 8]);
#pragma unroll
        for (int nt = 0; nt < NT; nt++) {
            short8 b = *(const short8*)(&Blds[(q * N + nt * 16 + l16) * 8]);
            acc[nt] = __builtin_amdgcn_mfma_f32_16x16x32_bf16(a, b, acc[nt], 0, 0, 0);
        }
    }
    // store C + fused el/er
    float pel[4][H], per[4][H];
#pragma unroll
    for (int i = 0; i < 4; i++)
#pragma unroll
        for (int hh = 0; hh < H; hh++) { pel[i][hh] = 0.f; per[i][hh] = 0.f; }
#pragma unroll
    for (int nt = 0; nt < NT; nt++) {
        int col = nt * 16 + l16;
        float alc = al[col], arc = ar[col];
        constexpr int HSH = LOGD - 4;  // head = nt >> HSH
        int hh = nt >> HSH;
#pragma unroll
        for (int i = 0; i < 4; i++) {
            int row = m0 + w * 16 + q * 4 + i;
            float v = acc[nt][i];
            if (row < M) C[(size_t)row * N + col] = v;
            pel[i][hh] += v * alc;
            per[i][hh] += v * arc;
        }
    }
#pragma unroll
    for (int i = 0; i < 4; i++) {
#pragma unroll
        for (int hh = 0; hh < H; hh++) {
            float vl = pel[i][hh], vr = per[i][hh];
#pragma unroll
            for (int m = 1; m < 16; m <<= 1) {
                vl += __shfl_xor(vl, m, 64);
                vr += __shfl_xor(vr, m, 64);
            }
            if (l16 == 0) {
                int row = m0 + w * 16 + q * 4 + i;
                if (row < M) { el[row * H + hh] = vl; er[row * H + hh] = vr; }
            }
        }
    }
}

// ---------------- final: node-mean @ mcls ----------------
__global__ __launch_bounds__(64) void final_kernel(const float* __restrict__ msum,
                                                   const float* __restrict__ mcls,
                                                   void* __restrict__ doutv,
                                                   const int* __restrict__ flag, int Nm) {
    int t = threadIdx.x;
    if (t < 15) {
        float inv = 1.f / (float)Nm;
        float acc = 0.f;
#pragma unroll
        for (int c = 0; c < 32; c++) acc += msum[c] * inv * mcls[c * 15 + t];
        if (*flag) ((float*)doutv)[t] = acc;
        else       ((ushort*)doutv)[t] = f2b(acc);
    }
}

extern "C" void kernel_launch(void* const* d_in, const int* in_sizes, int n_in,
                              void* d_out, int out_size, void* d_ws, size_t ws_size,
                              hipStream_t stream) {
    const int NP = 100000, NG = 2000, EP = 800000, NM = 2000, EM = 32000;

    const int* patch_src = (const int*)d_in[1];
    const int* patch_dst = (const int*)d_in[2];
    const int* patch_gid = (const int*)d_in[3];
    const int* mesh_src = (const int*)d_in[4];
    const int* mesh_dst = (const int*)d_in[5];

    // ---- workspace carve (256B aligned) ----
    char* p = (char*)d_ws;
    auto alloc = [&](size_t bytes) -> char* {
        char* r = p;
        p += (bytes + 255) & ~(size_t)255;
        return r;
    };
    char* zbase = p;  // zero-initialized region (convert zero slice)
    int* cnt_p = (int*)alloc((size_t)NP * 4);
    int* cursor_p = (int*)alloc((size_t)NP * 4);
    int* cnt_m = (int*)alloc((size_t)NM * 4);
    int* cursor_m = (int*)alloc((size_t)NM * 4);
    float* ro_sum = (float*)alloc((size_t)NG * 32 * 4);
    float* ro_cnt = (float*)alloc((size_t)NG * 4);
    float* msum = (float*)alloc(32 * 4);
    float* colbuf = (float*)alloc(6 * 1024 * 4);  // 6 slots of {sum[512], sumsq[512]}
    size_t zbytes = (size_t)(p - zbase);
    int* flag = (int*)alloc(256);
    int* off_p = (int*)alloc((size_t)(NP + 1) * 4);
    int* off_m = (int*)alloc((size_t)(NM + 1) * 4);
    int* bsum_p = (int*)alloc(64 * 4);
    int* bsum_m = (int*)alloc(16 * 4);
    int* csr_p = (int*)alloc((size_t)EP * 4);
    int* csr_m = (int*)alloc((size_t)EM * 4);
    float* el = (float*)alloc((size_t)NP * 4 * 4);
    float* er = (float*)alloc((size_t)NP * 4 * 4);
    float* hbuf = (float*)alloc((size_t)NP * 256 * 4);
    float* gbuf = (float*)alloc((size_t)NP * 256 * 4);
    float* hm = (float*)alloc((size_t)NM * 256 * 4);
    float* gm = (float*)alloc((size_t)NM * 256 * 4);
    float* elm = (float*)alloc((size_t)NM * 4 * 4);
    float* erm = (float*)alloc((size_t)NM * 4 * 4);
    float* ro_lin = (float*)alloc((size_t)NG * 32 * 4);
    float* ro_f = (float*)alloc((size_t)NG * 32 * 4);

    // converted fp32 copies of all float inputs + zero slice
    ConvArgs ca;
    float* convp[36];
    int conv_idx[36];
    conv_idx[0] = 0;
    for (int i = 1; i < 36; i++) conv_idx[i] = 5 + i;  // inputs 6..40
    for (int j = 0; j < 36; j++) {
        int ii = conv_idx[j];
        int n = in_sizes[ii];
        float* dd = (float*)alloc((size_t)n * 4);
        ca.s[j] = d_in[ii];
        ca.d[j] = dd;
        ca.n[j] = n;
        convp[j] = dd;
    }
    ca.s[36] = nullptr;  // zero slice
    ca.d[36] = (float*)zbase;
    ca.n[36] = (int)(zbytes / 4);

    const float* xf = convp[0];
    const float *pW1f = convp[1], *pal1f = convp[2], *par1f = convp[3];
    const float *pg1_gf = convp[4], *pg1_bf = convp[5], *pg1_af = convp[6];
    const float *pW2f = convp[7], *pal2f = convp[8], *par2f = convp[9];
    const float *pg2_gf = convp[10], *pg2_bf = convp[11], *pg2_af = convp[12];
    const float *pW3f = convp[13], *pal3f = convp[14], *par3f = convp[15];
    const float* pclsf = convp[16];
    const float *rn_gf = convp[17], *rn_bf2 = convp[18], *rn_af = convp[19];
    const float *mW1f = convp[20], *mal1f = convp[21], *mar1f = convp[22];
    const float *mg1_gf = convp[23], *mg1_bf = convp[24], *mg1_af = convp[25];
    const float *mW2f = convp[26], *mal2f = convp[27], *mar2f = convp[28];
    const float *mg2_gf = convp[29], *mg2_bf = convp[30], *mg2_af = convp[31];
    const float *mW3f = convp[32], *mal3f = convp[33], *mar3f = convp[34];
    const float* mclsf = convp[35];

    convert_kernel<<<dim3(16, 37), 256, 0, stream>>>(ca, (const ushort*)d_in[0], flag);

    // ---- CSR build (patch + mesh merged launches) ----
    const int SBP = (NP + 2047) / 2048, SBM = (NM + 2047) / 2048;
    hist_both<<<512 + 64, 256, 0, stream>>>(patch_dst, cnt_p, EP, mesh_dst, cnt_m, EM, 512);
    scan_both<<<SBP + SBM, 256, 0, stream>>>(cnt_p, off_p, bsum_p, NP, SBP, cnt_m, off_m, bsum_m, NM);
    fixup_both<<<SBP + SBM, 256, 0, stream>>>(bsum_p, off_p, NP, SBP, bsum_m, off_m, NM, SBM);
    scatter_both<<<512 + 64, 256, 0, stream>>>(patch_src, patch_dst, off_p, cursor_p, csr_p, EP,
                                               mesh_src, mesh_dst, off_m, cursor_m, csr_m, EM, 512);

    int gP = (NP + 3) / 4, gM = (NM + 3) / 4;
    int gT = (NP + 63) / 64, gTm = (NM + 63) / 64;
    float* cb0 = colbuf + 0 * 1024;
    float* cb1 = colbuf + 1 * 1024;
    float* cb2 = colbuf + 2 * 1024;
    float* cb3 = colbuf + 3 * 1024;
    float* cb4 = colbuf + 4 * 1024;

    // ---- patch GAT layer 1 (H=4, D=64): el/er, then on-the-fly h aggregation ----
    proj1_elr_kernel<<<gP, 256, 0, stream>>>(xf, pW1f, pal1f, par1f, el, er, NP);
    aggr1_fly_kernel<<<gP, 256, 0, stream>>>(xf, pW1f, el, er, off_p, csr_p, gbuf, NP);
    colstats_kernel<<<256, 256, 0, stream>>>(gbuf, cb0, cb0 + 512, NP);

    // ---- patch GAT layer 2 (H=3, D=64) ----
    gemm_kernel<256, 192, 3, 6, true><<<gT, 256, 0, stream>>>(
        gbuf, pW2f, cb0, pg1_gf, pg1_bf, pg1_af, pal2f, par2f, hbuf, el, er, NP);
    aggr4_kernel<3, 6, 192, 4><<<gP, 256, 0, stream>>>(hbuf, el, er, off_p, csr_p, gbuf, NP, 0.01f);
    colstats_kernel<<<256, 192, 0, stream>>>(gbuf, cb1, cb1 + 512, NP);

    // ---- patch GAT layer 3 (H=2, D=32) + head-mean + segment readout ----
    gemm_kernel<192, 64, 2, 5, true><<<gT, 256, 0, stream>>>(
        gbuf, pW3f, cb1, pg2_gf, pg2_bf, pg2_af, pal3f, par3f, hbuf, el, er, NP);
    aggr_mean_kernel<<<gP, 256, 0, stream>>>(hbuf, el, er, off_p, csr_p, patch_gid,
                                             ro_sum, ro_cnt, NP);

    // ---- readout: mean -> @pcls -> leaky -> GraphNorm (output 1 + mesh input) ----
    readout_kernel<<<(NG * 32 + 255) / 256, 256, 0, stream>>>(ro_sum, ro_cnt, pclsf, ro_lin, NG);
    colstats_kernel<<<64, 32, 0, stream>>>(ro_lin, cb2, cb2 + 512, NG);
    gnorm_apply_ro_kernel<<<64, 32, 0, stream>>>(ro_lin, cb2, cb2 + 512, rn_gf, rn_bf2, rn_af,
                                                 d_out, flag, ro_f, NG);

    // ---- mesh GAT layer 1 (H=4, D=64) ----
    gemm_kernel<32, 256, 4, 6, false><<<gTm, 256, 0, stream>>>(
        ro_f, mW1f, nullptr, nullptr, nullptr, nullptr, mal1f, mar1f, hm, elm, erm, NM);
    aggr4_kernel<4, 6, 256, 2><<<gM, 256, 0, stream>>>(hm, elm, erm, off_m, csr_m, gm, NM, 0.01f);
    colstats_kernel<<<64, 256, 0, stream>>>(gm, cb3, cb3 + 512, NM);

    // ---- mesh GAT layer 2 (H=3, D=32) ----
    gemm_kernel<256, 96, 3, 5, true><<<gTm, 256, 0, stream>>>(
        gm, mW2f, cb3, mg1_gf, mg1_bf, mg1_af, mal2f, mar2f, hm, elm, erm, NM);
    aggr4_kernel<3, 5, 96, 4><<<gM, 256, 0, stream>>>(hm, elm, erm, off_m, csr_m, gm, NM, 0.01f);
    colstats_kernel<<<64, 96, 0, stream>>>(gm, cb4, cb4 + 512, NM);

    // ---- mesh GAT layer 3 (H=2, D=32) + head-mean + node-mean ----
    gemm_kernel<96, 64, 2, 5, true><<<gTm, 256, 0, stream>>>(
        gm, mW3f, cb4, mg2_gf, mg2_bf, mg2_af, mal3f, mar3f, hm, elm, erm, NM);
    aggr_mean_kernel<<<gM, 256, 0, stream>>>(hm, elm, erm, off_m, csr_m, nullptr,
                                             msum, nullptr, NM);
    final_kernel<<<1, 64, 0, stream>>>(msum, mclsf, d_out, flag, NM);

    (void)n_in; (void)out_size; (void)ws_size;
}